// Round 8
// baseline (750.635 us; speedup 1.0000x reference)
//
#include <hip/hip_runtime.h>
#include <hip/hip_bf16.h>
#include <stdint.h>

#define NTOK 4096       // B*T
#define DMODEL 1024
#define DFF 4096
#define NE 8
#define MAXTILE 72      // max m-tiles: worst case 64 + 7 ceil slack

typedef __attribute__((ext_vector_type(8))) short short8;
typedef __attribute__((ext_vector_type(4))) float f32x4;

__device__ inline void gload_lds16(const void* g, void* l) {
  __builtin_amdgcn_global_load_lds(
      (const __attribute__((address_space(1))) unsigned int*)g,
      (__attribute__((address_space(3))) unsigned int*)l, 16, 0, 0);
}

// ---------- router: logits -> top2 -> softmax-over-top2 (+ fused x->bf16) ----------
__global__ void k_router(const float* __restrict__ x, const float* __restrict__ Wr,
                         int* __restrict__ cnt, int* __restrict__ tok_e,
                         float* __restrict__ tok_w, __hip_bfloat16* __restrict__ xb) {
  const int lane = threadIdx.x & 63;
  const int t = blockIdx.x * 4 + (threadIdx.x >> 6);
  const float* xr = x + (size_t)t * DMODEL;

  // fused bf16 conversion of this token's row (coalesced float4 -> ushort4)
  {
    const float4* xr4 = (const float4*)xr;
    ushort4* xb4 = (ushort4*)(xb + (size_t)t * DMODEL);
#pragma unroll
    for (int i = 0; i < 4; ++i) {
      float4 v = xr4[lane + 64 * i];
      __hip_bfloat16 q[4];
      q[0] = __float2bfloat16(v.x); q[1] = __float2bfloat16(v.y);
      q[2] = __float2bfloat16(v.z); q[3] = __float2bfloat16(v.w);
      xb4[lane + 64 * i] = *(ushort4*)q;
    }
  }

  float acc[NE];
#pragma unroll
  for (int e = 0; e < NE; ++e) acc[e] = 0.f;
  for (int c = lane; c < DMODEL; c += 64) {
    float xv = xr[c];
#pragma unroll
    for (int e = 0; e < NE; ++e) acc[e] += xv * Wr[e * DMODEL + c];
  }
#pragma unroll
  for (int e = 0; e < NE; ++e) {
#pragma unroll
    for (int off = 32; off >= 1; off >>= 1) acc[e] += __shfl_xor(acc[e], off);
  }
  if (lane == 0) {
    int e0 = 0; float m0 = acc[0];
#pragma unroll
    for (int e = 1; e < NE; ++e) if (acc[e] > m0) { m0 = acc[e]; e0 = e; }
    int e1 = -1; float m1 = -1e30f;
#pragma unroll
    for (int e = 0; e < NE; ++e) if (e != e0 && acc[e] > m1) { m1 = acc[e]; e1 = e; }
    float w0 = 1.f / (1.f + __expf(m1 - m0));   // softmax over top-2 (T=1)
    tok_e[2 * t] = e0; tok_e[2 * t + 1] = e1;
    tok_w[2 * t] = w0; tok_w[2 * t + 1] = 1.f - w0;
    atomicAdd(&cnt[e0], 1); atomicAdd(&cnt[e1], 1);
  }
}

// offsets + dense m-tile table: meta[0]=ntile, meta[1+i]=(e<<16)|m0
__global__ void k_offsets(const int* __restrict__ cnt, int* __restrict__ cursor,
                          int* __restrict__ off, int* __restrict__ meta) {
  if (threadIdx.x == 0) {
    int s = 0;
    for (int e = 0; e < NE; ++e) { off[e] = s; cursor[e] = s; s += cnt[e]; }
    off[NE] = s;
    int nt = 0;
    for (int e = 0; e < NE; ++e)
      for (int m0 = 0; m0 < cnt[e]; m0 += 128)
        meta[1 + nt++] = (e << 16) | m0;
    meta[0] = nt;
  }
}

__global__ void k_scatter(const int* __restrict__ tok_e, const float* __restrict__ tok_w,
                          int* __restrict__ cursor, int* __restrict__ pair_token,
                          float* __restrict__ pair_w) {
  const int t = blockIdx.x * blockDim.x + threadIdx.x;
  if (t >= NTOK) return;
#pragma unroll
  for (int k = 0; k < 2; ++k) {
    int e = tok_e[2 * t + k];
    int slot = atomicAdd(&cursor[e], 1);
    pair_token[slot] = t;
    pair_w[slot] = tok_w[2 * t + k];
  }
}

// ------- grouped GEMM, 128x128 tile, BK=64, 2-phase pipelined (dbuf LDS) -------
// PHASE 1: h[p, f] = silu( xb[tok(p), :] @ W1[e][f, :] )   (store bf16)
// PHASE 2: out[tok(p), d] += w(p) * ( h[p, :] @ W2[e][d, :] )
template <int PHASE>
__global__ __launch_bounds__(256, 2) void k_gemm(
    const __hip_bfloat16* __restrict__ A, const float* __restrict__ Bw,
    const int* __restrict__ off, const int* __restrict__ cnt,
    const int* __restrict__ meta,
    const int* __restrict__ pair_token, const float* __restrict__ pair_w,
    __hip_bfloat16* __restrict__ h, float* __restrict__ out, int BF, int fchunk) {
  if ((int)blockIdx.y >= meta[0]) return;          // dense tile table
  const int pk = meta[1 + blockIdx.y];
  const int e = pk >> 16;
  const int m0 = pk & 0xffff;
  const int cnt_e = cnt[e];
  const int off_e = off[e];
  const int nt = blockIdx.x;

  __shared__ __align__(16) __hip_bfloat16 Alds[2][128 * 64];
  __shared__ __align__(16) __hip_bfloat16 Blds[2][128 * 64];

  const int t = threadIdx.x;
  const int lane = t & 63;
  const int w = t >> 6, wr = w >> 1, wc = w & 1;

  const int K = (PHASE == 1) ? DMODEL : BF;
  const int Astride = (PHASE == 1) ? DMODEL : BF;
  const int Bstride = (PHASE == 1) ? DMODEL : DFF;
  const int NT = K >> 6;

  // per-thread A stage rows (gathered for PHASE 1)
  const __hip_bfloat16* arow[4];
  {
    int r = t >> 3;
#pragma unroll
    for (int i = 0; i < 4; ++i) {
      int gr = m0 + r + i * 32;
      if (gr > cnt_e - 1) gr = cnt_e - 1;
      int p = off_e + gr;
      size_t row = (PHASE == 1) ? (size_t)pair_token[p] : (size_t)p;
      arow[i] = A + row * Astride;
    }
  }
  const int ac = (t & 7) * 8;   // A k-offset (elements)

  const float* Bbase = (PHASE == 1)
      ? Bw + ((size_t)e * DFF + (size_t)fchunk * BF + (size_t)nt * 128) * DMODEL
      : Bw + ((size_t)e * DMODEL + (size_t)nt * 128) * DFF + (size_t)fchunk * BF;
  const int bl16 = t & 15;
  const int brow0 = t >> 4;

  f32x4 acc[4][4];
#pragma unroll
  for (int m = 0; m < 4; ++m)
#pragma unroll
    for (int n = 0; n < 4; ++n) acc[m][n] = (f32x4){0.f, 0.f, 0.f, 0.f};

  float4 breg[8];

  // ---- prologue: stage tile 0 (A -> LDS buf0 via DMA, B -> regs) ----
#pragma unroll
  for (int i = 0; i < 4; ++i)
    gload_lds16(arow[i] + ac, &Alds[0][((t >> 3) + i * 32) * 64 + ac]);
#pragma unroll
  for (int s = 0; s < 8; ++s)
    breg[s] = *(const float4*)(Bbase + (size_t)(s * 16 + brow0) * Bstride + bl16 * 4);
  asm volatile("s_waitcnt vmcnt(0)" ::: "memory");

  for (int t_ = 0; t_ < NT; ++t_) {
    const int cur = t_ & 1;
    // 1. cvt + ds_write current B tile (regs ready: drained last iter / prologue)
#pragma unroll
    for (int s = 0; s < 8; ++s) {
      int row = s * 16 + brow0;
      __hip_bfloat16 q[4];
      q[0] = __float2bfloat16(breg[s].x); q[1] = __float2bfloat16(breg[s].y);
      q[2] = __float2bfloat16(breg[s].z); q[3] = __float2bfloat16(breg[s].w);
      *(ushort4*)&Blds[cur][row * 64 + bl16 * 4] = *(ushort4*)q;
    }
    // 2. prefetch next tile (A -> other LDS buf, B -> regs); hidden under 3-4
    if (t_ + 1 < NT) {
      const int k0n = (t_ + 1) * 64;
#pragma unroll
      for (int i = 0; i < 4; ++i)
        gload_lds16(arow[i] + k0n + ac, &Alds[cur ^ 1][((t >> 3) + i * 32) * 64 + ac]);
#pragma unroll
      for (int s = 0; s < 8; ++s)
        breg[s] = *(const float4*)(Bbase + (size_t)(s * 16 + brow0) * Bstride + k0n + bl16 * 4);
    }
    // 3. make this tile's LDS visible to all waves
    asm volatile("s_waitcnt lgkmcnt(0)" ::: "memory");
    __builtin_amdgcn_s_barrier();
    // 4. MFMA on current tile
#pragma unroll
    for (int kk = 0; kk < 2; ++kk) {
      short8 af[4], bf_[4];
      const int ko = kk * 32 + (lane >> 4) * 8;
#pragma unroll
      for (int m = 0; m < 4; ++m)
        af[m] = *(const short8*)&Alds[cur][(wr * 64 + m * 16 + (lane & 15)) * 64 + ko];
#pragma unroll
      for (int n = 0; n < 4; ++n)
        bf_[n] = *(const short8*)&Blds[cur][(wc * 64 + n * 16 + (lane & 15)) * 64 + ko];
#pragma unroll
      for (int m = 0; m < 4; ++m)
#pragma unroll
        for (int n = 0; n < 4; ++n)
          acc[m][n] = __builtin_amdgcn_mfma_f32_16x16x32_bf16(af[m], bf_[n], acc[m][n], 0, 0, 0);
    }
    // 5. drain prefetch (issued one compute-phase ago) + buffer-reuse fence
    asm volatile("s_waitcnt vmcnt(0)" ::: "memory");
    __builtin_amdgcn_s_barrier();
  }

#pragma unroll
  for (int m = 0; m < 4; ++m) {
#pragma unroll
    for (int j = 0; j < 4; ++j) {
      const int lrow = wr * 64 + m * 16 + (lane >> 4) * 4 + j;
      const int grow = m0 + lrow;
      if (grow >= cnt_e) continue;
      const int p = off_e + grow;
      if (PHASE == 1) {
        __hip_bfloat16* hrow = h + (size_t)p * BF;
#pragma unroll
        for (int n = 0; n < 4; ++n) {
          int col = nt * 128 + wc * 64 + n * 16 + (lane & 15);
          float v = acc[m][n][j];
          v = v / (1.f + __expf(-v));          // SiLU
          hrow[col] = __float2bfloat16(v);
        }
      } else {
        const int tkn = pair_token[p];
        const float wgt = pair_w[p];
        float* orow = out + (size_t)tkn * DMODEL;
#pragma unroll
        for (int n = 0; n < 4; ++n) {
          int col = nt * 128 + wc * 64 + n * 16 + (lane & 15);
          atomicAdd(&orow[col], wgt * acc[m][n][j]);
        }
      }
    }
  }
}

extern "C" void kernel_launch(void* const* d_in, const int* in_sizes, int n_in,
                              void* d_out, int out_size, void* d_ws, size_t ws_size,
                              hipStream_t stream) {
  const float* x  = (const float*)d_in[0];
  const float* W1 = (const float*)d_in[1];
  const float* W2 = (const float*)d_in[2];
  const float* Wr = (const float*)d_in[3];
  float* out = (float*)d_out;

  char* ws = (char*)d_ws;
  int*   cnt        = (int*)(ws + 0);
  int*   cursor     = (int*)(ws + 256);
  int*   off        = (int*)(ws + 512);
  int*   meta       = (int*)(ws + 768);      // [0]=ntile, [1..] packed tiles
  int*   tok_e      = (int*)(ws + 2048);
  float* tok_w      = (float*)(ws + 2048 + 32768);
  int*   pair_token = (int*)(ws + 2048 + 65536);
  float* pair_w     = (float*)(ws + 2048 + 98304);
  __hip_bfloat16* xb = (__hip_bfloat16*)(ws + 133120);
  const size_t hoff = 133120 + (size_t)NTOK * DMODEL * 2;   // 8,521,728
  __hip_bfloat16* h = (__hip_bfloat16*)(ws + hoff);

  // adapt DFF chunking to workspace size (h is [2*NTOK][BF] bf16)
  int nchunk = 1;
  while (nchunk < 32 &&
         hoff + (unsigned long long)(2 * NTOK) * (DFF / nchunk) * 2ULL > ws_size)
    nchunk <<= 1;
  const int BF = DFF / nchunk;

  hipMemsetAsync(cnt, 0, 32, stream);
  hipMemsetAsync(d_out, 0, (size_t)out_size * sizeof(float), stream);

  k_router<<<NTOK / 4, 256, 0, stream>>>(x, Wr, cnt, tok_e, tok_w, xb);
  k_offsets<<<1, 64, 0, stream>>>(cnt, cursor, off, meta);
  k_scatter<<<NTOK / 256, 256, 0, stream>>>(tok_e, tok_w, cursor, pair_token, pair_w);

  for (int c = 0; c < nchunk; ++c) {
    k_gemm<1><<<dim3(BF / 128, MAXTILE, 1), 256, 0, stream>>>(
        xb, W1, off, cnt, meta, pair_token, pair_w, h, out, BF, c);
    k_gemm<2><<<dim3(DMODEL / 128, MAXTILE, 1), 256, 0, stream>>>(
        h, W2, off, cnt, meta, pair_token, pair_w, h, out, BF, c);
  }
}

// Round 9
// 678.451 us; speedup vs baseline: 1.1064x; 1.1064x over previous
//
#include <hip/hip_runtime.h>
#include <hip/hip_bf16.h>
#include <stdint.h>

#define NTOK 4096       // B*T
#define DMODEL 1024
#define DFF 4096
#define NE 8
#define MAXTILE 72      // max m-tiles: worst case 64 + 7 ceil slack

typedef __attribute__((ext_vector_type(8))) short short8;
typedef __attribute__((ext_vector_type(4))) float f32x4;

__device__ inline void gload_lds16(const void* g, void* l) {
  __builtin_amdgcn_global_load_lds(
      (const __attribute__((address_space(1))) unsigned int*)g,
      (__attribute__((address_space(3))) unsigned int*)l, 16, 0, 0);
}

// ---------- router: logits -> top2 -> softmax-over-top2 (+ fused x->bf16) ----------
__global__ void k_router(const float* __restrict__ x, const float* __restrict__ Wr,
                         int* __restrict__ cnt, int* __restrict__ tok_e,
                         float* __restrict__ tok_w, __hip_bfloat16* __restrict__ xb) {
  const int lane = threadIdx.x & 63;
  const int t = blockIdx.x * 4 + (threadIdx.x >> 6);
  const float* xr = x + (size_t)t * DMODEL;

  // fused bf16 conversion of this token's row (coalesced float4 -> ushort4)
  {
    const float4* xr4 = (const float4*)xr;
    ushort4* xb4 = (ushort4*)(xb + (size_t)t * DMODEL);
#pragma unroll
    for (int i = 0; i < 4; ++i) {
      float4 v = xr4[lane + 64 * i];
      __hip_bfloat16 q[4];
      q[0] = __float2bfloat16(v.x); q[1] = __float2bfloat16(v.y);
      q[2] = __float2bfloat16(v.z); q[3] = __float2bfloat16(v.w);
      xb4[lane + 64 * i] = *(ushort4*)q;
    }
  }

  float acc[NE];
#pragma unroll
  for (int e = 0; e < NE; ++e) acc[e] = 0.f;
  for (int c = lane; c < DMODEL; c += 64) {
    float xv = xr[c];
#pragma unroll
    for (int e = 0; e < NE; ++e) acc[e] += xv * Wr[e * DMODEL + c];
  }
#pragma unroll
  for (int e = 0; e < NE; ++e) {
#pragma unroll
    for (int off = 32; off >= 1; off >>= 1) acc[e] += __shfl_xor(acc[e], off);
  }
  if (lane == 0) {
    int e0 = 0; float m0 = acc[0];
#pragma unroll
    for (int e = 1; e < NE; ++e) if (acc[e] > m0) { m0 = acc[e]; e0 = e; }
    int e1 = -1; float m1 = -1e30f;
#pragma unroll
    for (int e = 0; e < NE; ++e) if (e != e0 && acc[e] > m1) { m1 = acc[e]; e1 = e; }
    float w0 = 1.f / (1.f + __expf(m1 - m0));   // softmax over top-2 (T=1)
    tok_e[2 * t] = e0; tok_e[2 * t + 1] = e1;
    tok_w[2 * t] = w0; tok_w[2 * t + 1] = 1.f - w0;
    atomicAdd(&cnt[e0], 1); atomicAdd(&cnt[e1], 1);
  }
}

// offsets + dense m-tile table: meta[0]=ntile, meta[1+i]=(e<<16)|m0
__global__ void k_offsets(const int* __restrict__ cnt, int* __restrict__ cursor,
                          int* __restrict__ off, int* __restrict__ meta) {
  if (threadIdx.x == 0) {
    int s = 0;
    for (int e = 0; e < NE; ++e) { off[e] = s; cursor[e] = s; s += cnt[e]; }
    off[NE] = s;
    int nt = 0;
    for (int e = 0; e < NE; ++e)
      for (int m0 = 0; m0 < cnt[e]; m0 += 128)
        meta[1 + nt++] = (e << 16) | m0;
    meta[0] = nt;
  }
}

__global__ void k_scatter(const int* __restrict__ tok_e, const float* __restrict__ tok_w,
                          int* __restrict__ cursor, int* __restrict__ pair_token,
                          float* __restrict__ pair_w) {
  const int t = blockIdx.x * blockDim.x + threadIdx.x;
  if (t >= NTOK) return;
#pragma unroll
  for (int k = 0; k < 2; ++k) {
    int e = tok_e[2 * t + k];
    int slot = atomicAdd(&cursor[e], 1);
    pair_token[slot] = t;
    pair_w[slot] = tok_w[2 * t + k];
  }
}

// ---- weight slice fp32 -> bf16: dst flat, row = i8>>log2row, col = i8&(rowlen-1) ----
// src element = src[row * src_stride + src_coloff + col]
__global__ void k_cvt_w(const float* __restrict__ src, __hip_bfloat16* __restrict__ dst,
                        int log2row, size_t src_stride, size_t src_coloff) {
  const size_t i8 = ((size_t)blockIdx.x * blockDim.x + threadIdx.x) * 8;
  const size_t row = i8 >> log2row;
  const size_t col = i8 & (((size_t)1 << log2row) - 1);
  const float4* s = (const float4*)(src + row * src_stride + src_coloff + col);
  float4 v0 = s[0], v1 = s[1];
  __hip_bfloat16 o8[8];
  o8[0] = __float2bfloat16(v0.x); o8[1] = __float2bfloat16(v0.y);
  o8[2] = __float2bfloat16(v0.z); o8[3] = __float2bfloat16(v0.w);
  o8[4] = __float2bfloat16(v1.x); o8[5] = __float2bfloat16(v1.y);
  o8[6] = __float2bfloat16(v1.z); o8[7] = __float2bfloat16(v1.w);
  *reinterpret_cast<float4*>(&dst[i8]) = *reinterpret_cast<float4*>(o8);
}

// ------ grouped GEMM, m97 structure: 128x128 tile, BK=64, A+B via global_load_lds ------
// PHASE 1: h[p, f] = silu( xb[tok(p), :] @ w1b[e][f, :] )   (store bf16)
// PHASE 2: out[tok(p), d] += w(p) * ( h[p, :] @ w2b[e][d, :] )
template <int PHASE>
__global__ __launch_bounds__(256, 4) void k_gemm(
    const __hip_bfloat16* __restrict__ A, const __hip_bfloat16* __restrict__ Bw,
    const int* __restrict__ off, const int* __restrict__ cnt,
    const int* __restrict__ meta,
    const int* __restrict__ pair_token, const float* __restrict__ pair_w,
    __hip_bfloat16* __restrict__ h, float* __restrict__ out, int BF) {
  if ((int)blockIdx.y >= meta[0]) return;          // dense tile table
  const int pk = meta[1 + blockIdx.y];
  const int e = pk >> 16;
  const int m0 = pk & 0xffff;
  const int cnt_e = cnt[e];
  const int off_e = off[e];
  const int nt = blockIdx.x;

  __shared__ __align__(16) __hip_bfloat16 Alds[128 * 64];
  __shared__ __align__(16) __hip_bfloat16 Blds[128 * 64];

  const int t = threadIdx.x;
  const int lane = t & 63;
  const int w = t >> 6, wr = w >> 1, wc = w & 1;

  const int K = (PHASE == 1) ? DMODEL : BF;
  const int Astride = (PHASE == 1) ? DMODEL : BF;
  const int Bstride = (PHASE == 1) ? DMODEL : BF;

  // per-thread A stage rows (gathered for PHASE 1)
  const __hip_bfloat16* arow[4];
  {
    int r = t >> 3;
#pragma unroll
    for (int i = 0; i < 4; ++i) {
      int gr = m0 + r + i * 32;
      if (gr > cnt_e - 1) gr = cnt_e - 1;
      int p = off_e + gr;
      size_t row = (PHASE == 1) ? (size_t)pair_token[p] : (size_t)p;
      arow[i] = A + row * Astride;
    }
  }
  // per-thread B stage rows (bf16 weights, chunk-local layout)
  const __hip_bfloat16* Bbase = (PHASE == 1)
      ? Bw + ((size_t)e * DFF /*BF rows per e, stride DMODEL*/ * 0 + (size_t)e * BF + (size_t)nt * 128) * DMODEL
      : Bw + ((size_t)e * DMODEL + (size_t)nt * 128) * BF;
  const __hip_bfloat16* brow[4];
  {
    int r = t >> 3;
#pragma unroll
    for (int i = 0; i < 4; ++i)
      brow[i] = Bbase + (size_t)(r + i * 32) * Bstride;
  }
  const int ac = (t & 7) * 8;   // k-offset (elements), 16B per lane

  f32x4 acc[4][4];
#pragma unroll
  for (int m = 0; m < 4; ++m)
#pragma unroll
    for (int n = 0; n < 4; ++n) acc[m][n] = (f32x4){0.f, 0.f, 0.f, 0.f};

  for (int k0 = 0; k0 < K; k0 += 64) {
    __syncthreads();
    // A and B: bf16, async global->LDS, 16B/lane, linear [128][64]
#pragma unroll
    for (int i = 0; i < 4; ++i)
      gload_lds16(arow[i] + k0 + ac, &Alds[((t >> 3) + i * 32) * 64 + ac]);
#pragma unroll
    for (int i = 0; i < 4; ++i)
      gload_lds16(brow[i] + k0 + ac, &Blds[((t >> 3) + i * 32) * 64 + ac]);
    __syncthreads();
#pragma unroll
    for (int kk = 0; kk < 2; ++kk) {
      short8 af[4], bf_[4];
      const int ko = kk * 32 + (lane >> 4) * 8;
#pragma unroll
      for (int m = 0; m < 4; ++m)
        af[m] = *(const short8*)&Alds[(wr * 64 + m * 16 + (lane & 15)) * 64 + ko];
#pragma unroll
      for (int n = 0; n < 4; ++n)
        bf_[n] = *(const short8*)&Blds[(wc * 64 + n * 16 + (lane & 15)) * 64 + ko];
#pragma unroll
      for (int m = 0; m < 4; ++m)
#pragma unroll
        for (int n = 0; n < 4; ++n)
          acc[m][n] = __builtin_amdgcn_mfma_f32_16x16x32_bf16(af[m], bf_[n], acc[m][n], 0, 0, 0);
    }
  }

#pragma unroll
  for (int m = 0; m < 4; ++m) {
#pragma unroll
    for (int j = 0; j < 4; ++j) {
      const int lrow = wr * 64 + m * 16 + (lane >> 4) * 4 + j;
      const int grow = m0 + lrow;
      if (grow >= cnt_e) continue;
      const int p = off_e + grow;
      if (PHASE == 1) {
        __hip_bfloat16* hrow = h + (size_t)p * BF;
#pragma unroll
        for (int n = 0; n < 4; ++n) {
          int col = nt * 128 + wc * 64 + n * 16 + (lane & 15);
          float v = acc[m][n][j];
          v = v / (1.f + __expf(-v));          // SiLU
          hrow[col] = __float2bfloat16(v);
        }
      } else {
        const int tkn = pair_token[p];
        const float wgt = pair_w[p];
        float* orow = out + (size_t)tkn * DMODEL;
#pragma unroll
        for (int n = 0; n < 4; ++n) {
          int col = nt * 128 + wc * 64 + n * 16 + (lane & 15);
          atomicAdd(&orow[col], wgt * acc[m][n][j]);
        }
      }
    }
  }
}

extern "C" void kernel_launch(void* const* d_in, const int* in_sizes, int n_in,
                              void* d_out, int out_size, void* d_ws, size_t ws_size,
                              hipStream_t stream) {
  const float* x  = (const float*)d_in[0];
  const float* W1 = (const float*)d_in[1];
  const float* W2 = (const float*)d_in[2];
  const float* Wr = (const float*)d_in[3];
  float* out = (float*)d_out;

  char* ws = (char*)d_ws;
  int*   cnt        = (int*)(ws + 0);
  int*   cursor     = (int*)(ws + 256);
  int*   off        = (int*)(ws + 512);
  int*   meta       = (int*)(ws + 768);      // [0]=ntile, [1..] packed tiles
  int*   tok_e      = (int*)(ws + 2048);
  float* tok_w      = (float*)(ws + 2048 + 32768);
  int*   pair_token = (int*)(ws + 2048 + 65536);
  float* pair_w     = (float*)(ws + 2048 + 98304);
  __hip_bfloat16* xb = (__hip_bfloat16*)(ws + 133120);
  const size_t dynoff = 133120 + (size_t)NTOK * DMODEL * 2;   // 16,910,336

  // choose DFF chunk: need w1b + w2b + h, each E*BF*DMODEL*2 / 2*NTOK*BF*2 bytes
  int nchunk = 1;
  while (nchunk < 32 &&
         dynoff + 49152ULL * (DFF / nchunk) > ws_size)
    nchunk <<= 1;
  const int BF = DFF / nchunk;

  __hip_bfloat16* w1b = (__hip_bfloat16*)(ws + dynoff);
  __hip_bfloat16* w2b = w1b + (size_t)NE * BF * DMODEL;
  __hip_bfloat16* h   = w2b + (size_t)NE * DMODEL * BF;

  hipMemsetAsync(cnt, 0, 32, stream);
  hipMemsetAsync(d_out, 0, (size_t)out_size * sizeof(float), stream);

  k_router<<<NTOK / 4, 256, 0, stream>>>(x, Wr, cnt, tok_e, tok_w, xb);
  k_offsets<<<1, 64, 0, stream>>>(cnt, cursor, off, meta);
  k_scatter<<<NTOK / 256, 256, 0, stream>>>(tok_e, tok_w, cursor, pair_token, pair_w);

  // log2 of flat row lengths (all pow2: BF in {4096..128})
  int lg_bfdm = 0; while ((1 << lg_bfdm) < BF * DMODEL) ++lg_bfdm;
  int lg_bf   = 0; while ((1 << lg_bf)   < BF)          ++lg_bf;
  const int cvt_blocks = NE * BF * DMODEL / 8 / 256;

  for (int c = 0; c < nchunk; ++c) {
    // w1b[e][f][d] = bf16(W1[e][c*BF+f][d]) : row=e, rowlen=BF*DMODEL
    k_cvt_w<<<cvt_blocks, 256, 0, stream>>>(
        W1, w1b, lg_bfdm, (size_t)DFF * DMODEL, (size_t)c * BF * DMODEL);
    // w2b[e][d][f] = bf16(W2[e][d][c*BF+f]) : row=e*DMODEL+d, rowlen=BF
    k_cvt_w<<<cvt_blocks, 256, 0, stream>>>(
        W2, w2b, lg_bf, (size_t)DFF, (size_t)c * BF);

    k_gemm<1><<<dim3(BF / 128, MAXTILE, 1), 256, 0, stream>>>(
        xb, w1b, off, cnt, meta, pair_token, pair_w, h, out, BF);
    k_gemm<2><<<dim3(DMODEL / 128, MAXTILE, 1), 256, 0, stream>>>(
        h, w2b, off, cnt, meta, pair_token, pair_w, h, out, BF);
  }
}